// Round 5
// baseline (290.327 us; speedup 1.0000x reference)
//
#include <hip/hip_runtime.h>

typedef __attribute__((ext_vector_type(8))) short short8;
typedef __attribute__((ext_vector_type(4))) float f32x4;
typedef __attribute__((ext_vector_type(4))) float float4v;
typedef __attribute__((ext_vector_type(4))) unsigned short ushort4v;
typedef unsigned short u16;

#define MFMA16(a, b, c) __builtin_amdgcn_mfma_f32_16x16x32_bf16((a), (b), (c), 0, 0, 0)

#define W_ 128
#define C_ 256
#define XA_LD 136   // region A row stride: x-chunk [128][136] bf16, later vT [128][136]
#define QK_LD 40    // q,k [128][40] inside region C (16B-aligned rows)
#define P_LD 136    // p [128][136] over region C

__device__ __forceinline__ u16 f2bf(float f) {
    unsigned u = __builtin_bit_cast(unsigned, f);
    u += 0x7fffu + ((u >> 16) & 1u);   // RNE
    return (u16)(u >> 16);
}

// Pack weights into MFMA B-fragment order (bf16):
// pack[((kt*NCT + ct)*64 + lane)*8 + j] = w[kt*32 + (lane>>4)*8 + j][ct*16 + (lane&15)]
__global__ __launch_bounds__(256) void prep_pack(const float* __restrict__ wq,
                                                 const float* __restrict__ wk,
                                                 const float* __restrict__ wv,
                                                 u16* __restrict__ pack) {
    int t = blockIdx.x * 256 + threadIdx.x;   // 0 .. 81919
    int j = t & 7;
    int l = (t >> 3) & 63;
    int kr = ((l >> 4) << 3) + j;   // k offset within 32-chunk
    int lm = l & 15;
    if (t < 8192) {                 // wq: [256][32], NCT=2
        int g = t >> 9, ct = g & 1, kt = g >> 1;
        pack[t] = f2bf(wq[(kt * 32 + kr) * 32 + ct * 16 + lm]);
    } else if (t < 16384) {         // wk
        int u = t - 8192;
        int g = u >> 9, ct = g & 1, kt = g >> 1;
        pack[t] = f2bf(wk[(kt * 32 + kr) * 32 + ct * 16 + lm]);
    } else {                        // wv: [256][256], NCT=16
        int u = t - 16384;
        int g = u >> 9, ct = g & 15, kt = g >> 4;
        pack[t] = f2bf(wv[(kt * 32 + kr) * 256 + ct * 16 + lm]);
    }
}

// One block = one (b,h) slice x one output-column half (128 of 256 cols).
// 8 waves x 16 rows. LDS: regA (x-chunk -> vT) + regC (q,k -> p) = 69632 B
// -> 2 blocks/CU, 16 waves/CU.
__global__ __launch_bounds__(512, 4) void attn_fused(
        const float* __restrict__ x,
        const u16* __restrict__ wq_p, const u16* __restrict__ wk_p,
        const u16* __restrict__ wv_p,
        const float* __restrict__ bq, const float* __restrict__ bk,
        const float* __restrict__ bv,
        float* __restrict__ out) {
    __shared__ u16 uA[W_ * XA_LD];   // 34816 B: x chunk, then vT[c][w']
    __shared__ u16 uC[W_ * P_LD];    // 34816 B: uQ [0,5120), uK [5120,10240) (elems), then p

    // XCD-pairing swizzle: blocks 2s,2s+1 (same slice) land on the same XCD.
    const int wg = ((int)blockIdx.x & 7) * 512 + ((int)blockIdx.x >> 3);
    const int slice = wg >> 1;           // b*H + h
    const int half = wg & 1;             // output-column half
    const int tid = threadIdx.x;
    const int lane = tid & 63;
    const int wid = tid >> 6;            // 0..7
    const int lm = lane & 15;
    const int lq = lane >> 4;
    const int rowbase = wid * 16;        // wave owns rows [rowbase, rowbase+16)
    const float* xs = x + (size_t)slice * (W_ * C_);

    f32x4 qa[2] = {};    // q accum [ct]
    f32x4 ka[2] = {};    // k accum [ct]
    f32x4 vac[8] = {};   // v accum for this col-half [ct]

    // ---------------- Projections: stream x in two K-chunks ----------------
    for (int c = 0; c < 2; ++c) {
        {   // load chunk c: x[:, c*128 .. c*128+128) -> uA bf16
            int r0 = tid >> 5;               // 0..15
            int col = (tid & 31) * 4;        // 0..124
#pragma unroll
            for (int p = 0; p < 8; ++p) {
                int row = p * 16 + r0;
                float4v xv = *reinterpret_cast<const float4v*>(xs + row * C_ + c * 128 + col);
                ushort4v b4;
                b4[0] = f2bf(xv[0]); b4[1] = f2bf(xv[1]);
                b4[2] = f2bf(xv[2]); b4[3] = f2bf(xv[3]);
                *reinterpret_cast<ushort4v*>(&uA[row * XA_LD + col]) = b4;
            }
        }
        __syncthreads();
#pragma unroll
        for (int kt = 0; kt < 4; ++kt) {
            short8 a = *reinterpret_cast<const short8*>(&uA[(rowbase + lm) * XA_LD + kt * 32 + lq * 8]);
            int ktg = c * 4 + kt;
#pragma unroll
            for (int ct = 0; ct < 2; ++ct) {
                short8 bqf = *reinterpret_cast<const short8*>(wq_p + ((size_t)((ktg * 2 + ct) * 64 + lane)) * 8);
                short8 bkf = *reinterpret_cast<const short8*>(wk_p + ((size_t)((ktg * 2 + ct) * 64 + lane)) * 8);
                qa[ct] = MFMA16(a, bqf, qa[ct]);
                ka[ct] = MFMA16(a, bkf, ka[ct]);
            }
#pragma unroll
            for (int ct = 0; ct < 8; ++ct) {
                short8 bvf = *reinterpret_cast<const short8*>(wv_p + ((size_t)((ktg * 16 + half * 8 + ct) * 64 + lane)) * 8);
                vac[ct] = MFMA16(a, bvf, vac[ct]);
            }
        }
        __syncthreads();   // all chunk reads done before reuse of uA
    }

    // ---------------- q,k (+bias) -> region C ----------------
#pragma unroll
    for (int ct = 0; ct < 2; ++ct) {
        float bqv = bq[ct * 16 + lm];
        float bkv = bk[ct * 16 + lm];
#pragma unroll
        for (int r = 0; r < 4; ++r) {
            int row = rowbase + lq * 4 + r;
            uC[row * QK_LD + ct * 16 + lm] = f2bf(qa[ct][r] + bqv);
            uC[W_ * QK_LD + row * QK_LD + ct * 16 + lm] = f2bf(ka[ct][r] + bkv);
        }
    }
    __syncthreads();   // q,k visible to all waves

    // ---------------- vT (+bias) over region A ----------------
#pragma unroll
    for (int ct = 0; ct < 8; ++ct) {
        float bvv = bv[half * 128 + ct * 16 + lm];
        ushort4v pk;
#pragma unroll
        for (int r = 0; r < 4; ++r) pk[r] = f2bf(vac[ct][r] + bvv);
        // vT[c][w']: this wave owns w' rows [rowbase, rowbase+16)
        *reinterpret_cast<ushort4v*>(&uA[(ct * 16 + lm) * XA_LD + rowbase + lq * 4]) = pk;
    }

    // ---------------- scores = q @ k^T (K=32, single A-frag) ----------------
    f32x4 s[8];
    {
        short8 aq = *reinterpret_cast<const short8*>(&uC[(rowbase + lm) * QK_LD + lq * 8]);
        f32x4 zero = {0.f, 0.f, 0.f, 0.f};
#pragma unroll
        for (int ct = 0; ct < 8; ++ct) {
            short8 bk8 = *reinterpret_cast<const short8*>(&uC[W_ * QK_LD + (ct * 16 + lm) * QK_LD + lq * 8]);
            s[ct] = MFMA16(aq, bk8, zero);
        }
    }
    __syncthreads();   // vT visible; all q/k reads done before p overwrites region C

    // ---------------- softmax -> p over region C ----------------
#pragma unroll
    for (int r = 0; r < 4; ++r) {
        float m = s[0][r];
#pragma unroll
        for (int ct = 1; ct < 8; ++ct) m = fmaxf(m, s[ct][r]);
        m = fmaxf(m, __shfl_xor(m, 1));
        m = fmaxf(m, __shfl_xor(m, 2));
        m = fmaxf(m, __shfl_xor(m, 4));
        m = fmaxf(m, __shfl_xor(m, 8));
        float e[8];
        float sum = 0.f;
#pragma unroll
        for (int ct = 0; ct < 8; ++ct) {
            e[ct] = __expf(s[ct][r] - m);
            sum += e[ct];
        }
        sum += __shfl_xor(sum, 1);
        sum += __shfl_xor(sum, 2);
        sum += __shfl_xor(sum, 4);
        sum += __shfl_xor(sum, 8);
        float inv = 1.0f / sum;
        int row = rowbase + lq * 4 + r;
#pragma unroll
        for (int ct = 0; ct < 8; ++ct)
            uC[row * P_LD + ct * 16 + lm] = f2bf(e[ct] * inv);
    }
    // p rows are wave-local (written and read by the same wave) -> no barrier;
    // compiler orders the ds_write->ds_read dependence via lgkmcnt.

    // ---------------- out = p @ v (this col-half) ----------------
    {
        f32x4 oac[8] = {};
#pragma unroll
        for (int kt = 0; kt < 4; ++kt) {
            short8 pa = *reinterpret_cast<const short8*>(&uC[(rowbase + lm) * P_LD + kt * 32 + lq * 8]);
#pragma unroll
            for (int ct = 0; ct < 8; ++ct) {
                short8 vb = *reinterpret_cast<const short8*>(&uA[(ct * 16 + lm) * XA_LD + kt * 32 + lq * 8]);
                oac[ct] = MFMA16(pa, vb, oac[ct]);
            }
        }
        float* os = out + (size_t)slice * (W_ * C_) + half * 128;
#pragma unroll
        for (int ct = 0; ct < 8; ++ct)
#pragma unroll
            for (int r = 0; r < 4; ++r)
                os[(rowbase + lq * 4 + r) * C_ + ct * 16 + lm] = oac[ct][r];
    }
}

extern "C" void kernel_launch(void* const* d_in, const int* in_sizes, int n_in,
                              void* d_out, int out_size, void* d_ws, size_t ws_size,
                              hipStream_t stream) {
    const float* x  = (const float*)d_in[0];
    const float* wq = (const float*)d_in[1];
    const float* bq = (const float*)d_in[2];
    const float* wk = (const float*)d_in[3];
    const float* bk = (const float*)d_in[4];
    const float* wv = (const float*)d_in[5];
    const float* bv = (const float*)d_in[6];
    float* out = (float*)d_out;
    u16* pack = (u16*)d_ws;   // wq_p: 8192, wk_p: 8192, wv_p: 65536 u16

    prep_pack<<<320, 256, 0, stream>>>(wq, wk, wv, pack);
    attn_fused<<<4096, 512, 0, stream>>>(x, pack, pack + 8192, pack + 16384,
                                         bq, bk, bv, out);
}

// Round 6
// 289.263 us; speedup vs baseline: 1.0037x; 1.0037x over previous
//
#include <hip/hip_runtime.h>

typedef __attribute__((ext_vector_type(8))) short short8;
typedef __attribute__((ext_vector_type(4))) float f32x4;
typedef __attribute__((ext_vector_type(4))) float float4v;
typedef __attribute__((ext_vector_type(4))) unsigned short ushort4v;
typedef unsigned short u16;

#define MFMA16(a, b, c) __builtin_amdgcn_mfma_f32_16x16x32_bf16((a), (b), (c), 0, 0, 0)

#define W_ 128
#define C_ 256
#define A_LD 136    // region A row stride: x-chunk [128][136] bf16, later vT-half [128][136]
#define QK_LD 40    // q,k [128][40] inside region C
#define P_LD 136    // p [128][136] over region C

__device__ __forceinline__ u16 f2bf(float f) {
    unsigned u = __builtin_bit_cast(unsigned, f);
    u += 0x7fffu + ((u >> 16) & 1u);   // RNE
    return (u16)(u >> 16);
}

// Pack weights into MFMA B-fragment order (bf16):
// pack[((kt*NCT + ct)*64 + lane)*8 + j] = w[kt*32 + (lane>>4)*8 + j][ct*16 + (lane&15)]
__global__ __launch_bounds__(256) void prep_pack(const float* __restrict__ wq,
                                                 const float* __restrict__ wk,
                                                 const float* __restrict__ wv,
                                                 u16* __restrict__ pack) {
    int t = blockIdx.x * 256 + threadIdx.x;   // 0 .. 81919
    int j = t & 7;
    int l = (t >> 3) & 63;
    int kr = ((l >> 4) << 3) + j;   // k offset within 32-chunk
    int lm = l & 15;
    if (t < 8192) {                 // wq: [256][32], NCT=2
        int g = t >> 9, ct = g & 1, kt = g >> 1;
        pack[t] = f2bf(wq[(kt * 32 + kr) * 32 + ct * 16 + lm]);
    } else if (t < 16384) {         // wk
        int u = t - 8192;
        int g = u >> 9, ct = g & 1, kt = g >> 1;
        pack[t] = f2bf(wk[(kt * 32 + kr) * 32 + ct * 16 + lm]);
    } else {                        // wv: [256][256], NCT=16
        int u = t - 16384;
        int g = u >> 9, ct = g & 15, kt = g >> 4;
        pack[t] = f2bf(wv[(kt * 32 + kr) * 256 + ct * 16 + lm]);
    }
}

// One block per (b,h) slice. 4 waves x 32 rows (R4 partition).
// LDS: regA 34816 + regC 34816 = 69632 B -> 2 blocks/CU, 8 waves/CU.
__global__ __launch_bounds__(256, 2) void attn_fused(
        const float* __restrict__ x,
        const u16* __restrict__ wq_p, const u16* __restrict__ wk_p,
        const u16* __restrict__ wv_p,
        const float* __restrict__ bq, const float* __restrict__ bk,
        const float* __restrict__ bv,
        float* __restrict__ out) {
    __shared__ u16 uA[W_ * A_LD];   // x chunk -> vT half0 -> vT half1
    __shared__ u16 uC[W_ * P_LD];   // q [0,5120) k [5120,10240) elems -> p [128][136]

    const int slice = blockIdx.x;        // b*H + h
    const int tid = threadIdx.x;
    const int lane = tid & 63;
    const int wid = tid >> 6;            // 0..3
    const int lm = lane & 15;
    const int lq = lane >> 4;
    const int rowbase = wid * 32;        // wave owns rows [rowbase, rowbase+32)
    const float* xs = x + (size_t)slice * (W_ * C_);

    f32x4 qa[2][2] = {};     // [rt][ct]
    f32x4 ka[2][2] = {};
    f32x4 vac[2][16] = {};   // v accum, all 256 cols

    // ---------------- Projections: stream x in two K=128 chunks ----------------
    for (int c = 0; c < 2; ++c) {
        {   // stage x[:, c*128 .. c*128+128) -> uA bf16
            int r0 = tid >> 5;               // 0..7
            int col = (tid & 31) * 4;        // 0..124
#pragma unroll
            for (int p = 0; p < 16; ++p) {
                int row = p * 8 + r0;
                float4v xv = *reinterpret_cast<const float4v*>(xs + row * C_ + c * 128 + col);
                ushort4v b4;
                b4[0] = f2bf(xv[0]); b4[1] = f2bf(xv[1]);
                b4[2] = f2bf(xv[2]); b4[3] = f2bf(xv[3]);
                *reinterpret_cast<ushort4v*>(&uA[row * A_LD + col]) = b4;
            }
        }
        __syncthreads();
#pragma unroll
        for (int kt = 0; kt < 4; ++kt) {
            short8 a0 = *reinterpret_cast<const short8*>(&uA[(rowbase + lm) * A_LD + kt * 32 + lq * 8]);
            short8 a1 = *reinterpret_cast<const short8*>(&uA[(rowbase + 16 + lm) * A_LD + kt * 32 + lq * 8]);
            int ktg = c * 4 + kt;
#pragma unroll
            for (int ct = 0; ct < 2; ++ct) {
                short8 bqf = *reinterpret_cast<const short8*>(wq_p + ((size_t)((ktg * 2 + ct) * 64 + lane)) * 8);
                short8 bkf = *reinterpret_cast<const short8*>(wk_p + ((size_t)((ktg * 2 + ct) * 64 + lane)) * 8);
                qa[0][ct] = MFMA16(a0, bqf, qa[0][ct]);
                qa[1][ct] = MFMA16(a1, bqf, qa[1][ct]);
                ka[0][ct] = MFMA16(a0, bkf, ka[0][ct]);
                ka[1][ct] = MFMA16(a1, bkf, ka[1][ct]);
            }
#pragma unroll
            for (int ct = 0; ct < 16; ++ct) {
                short8 bvf = *reinterpret_cast<const short8*>(wv_p + ((size_t)((ktg * 16 + ct) * 64 + lane)) * 8);
                vac[0][ct] = MFMA16(a0, bvf, vac[0][ct]);
                vac[1][ct] = MFMA16(a1, bvf, vac[1][ct]);
            }
        }
        __syncthreads();   // all chunk reads done before uA reuse
    }

    // ---------------- q,k (+bias) -> region C ; vT half0 (+bias) -> region A ----------------
#pragma unroll
    for (int rt = 0; rt < 2; ++rt)
#pragma unroll
        for (int ct = 0; ct < 2; ++ct) {
            float bqv = bq[ct * 16 + lm];
            float bkv = bk[ct * 16 + lm];
#pragma unroll
            for (int r = 0; r < 4; ++r) {
                int row = rowbase + rt * 16 + lq * 4 + r;
                uC[row * QK_LD + ct * 16 + lm] = f2bf(qa[rt][ct][r] + bqv);
                uC[W_ * QK_LD + row * QK_LD + ct * 16 + lm] = f2bf(ka[rt][ct][r] + bkv);
            }
        }
#pragma unroll
    for (int ct = 0; ct < 8; ++ct) {
        float bvv = bv[ct * 16 + lm];
#pragma unroll
        for (int rt = 0; rt < 2; ++rt) {
            int wrow = rowbase + rt * 16 + lq * 4;
            ushort4v pk;
#pragma unroll
            for (int r = 0; r < 4; ++r) pk[r] = f2bf(vac[rt][ct][r] + bvv);
            *reinterpret_cast<ushort4v*>(&uA[(ct * 16 + lm) * A_LD + wrow]) = pk;
        }
    }
    __syncthreads();   // q,k,vT0 visible to all waves

    // ---------------- scores = q @ k^T ----------------
    f32x4 s[2][8];
    {
        short8 aq0 = *reinterpret_cast<const short8*>(&uC[(rowbase + lm) * QK_LD + lq * 8]);
        short8 aq1 = *reinterpret_cast<const short8*>(&uC[(rowbase + 16 + lm) * QK_LD + lq * 8]);
        f32x4 zero = {0.f, 0.f, 0.f, 0.f};
#pragma unroll
        for (int ct = 0; ct < 8; ++ct) {
            short8 bk8 = *reinterpret_cast<const short8*>(&uC[W_ * QK_LD + (ct * 16 + lm) * QK_LD + lq * 8]);
            s[0][ct] = MFMA16(aq0, bk8, zero);
            s[1][ct] = MFMA16(aq1, bk8, zero);
        }
    }
    __syncthreads();   // all q/k reads done before p overwrites region C

    // ---------------- softmax -> p over region C (wave-local rows) ----------------
#pragma unroll
    for (int rt = 0; rt < 2; ++rt) {
#pragma unroll
        for (int r = 0; r < 4; ++r) {
            float m = s[rt][0][r];
#pragma unroll
            for (int ct = 1; ct < 8; ++ct) m = fmaxf(m, s[rt][ct][r]);
            m = fmaxf(m, __shfl_xor(m, 1));
            m = fmaxf(m, __shfl_xor(m, 2));
            m = fmaxf(m, __shfl_xor(m, 4));
            m = fmaxf(m, __shfl_xor(m, 8));
            float e[8];
            float sum = 0.f;
#pragma unroll
            for (int ct = 0; ct < 8; ++ct) {
                e[ct] = __expf(s[rt][ct][r] - m);
                sum += e[ct];
            }
            sum += __shfl_xor(sum, 1);
            sum += __shfl_xor(sum, 2);
            sum += __shfl_xor(sum, 4);
            sum += __shfl_xor(sum, 8);
            float inv = 1.0f / sum;
            int row = rowbase + rt * 16 + lq * 4 + r;
#pragma unroll
            for (int ct = 0; ct < 8; ++ct)
                uC[row * P_LD + ct * 16 + lm] = f2bf(e[ct] * inv);
        }
    }
    // p rows are wave-local (written+read by same wave) -> no barrier needed

    float* os = out + (size_t)slice * (W_ * C_);

    // ---------------- PV half0: out[:, 0:128) = p @ v0 ----------------
    f32x4 oac[2][8] = {};
#pragma unroll
    for (int kt = 0; kt < 4; ++kt) {
        short8 pa0 = *reinterpret_cast<const short8*>(&uC[(rowbase + lm) * P_LD + kt * 32 + lq * 8]);
        short8 pa1 = *reinterpret_cast<const short8*>(&uC[(rowbase + 16 + lm) * P_LD + kt * 32 + lq * 8]);
#pragma unroll
        for (int ct = 0; ct < 8; ++ct) {
            short8 vb = *reinterpret_cast<const short8*>(&uA[(ct * 16 + lm) * A_LD + kt * 32 + lq * 8]);
            oac[0][ct] = MFMA16(pa0, vb, oac[0][ct]);
            oac[1][ct] = MFMA16(pa1, vb, oac[1][ct]);
        }
    }
    __syncthreads();   // all vT0 reads done before vT1 overwrites region A

    // ---------------- vT half1 -> region A ; store out half0 ----------------
#pragma unroll
    for (int ct = 0; ct < 8; ++ct) {
        float bvv = bv[128 + ct * 16 + lm];
#pragma unroll
        for (int rt = 0; rt < 2; ++rt) {
            int wrow = rowbase + rt * 16 + lq * 4;
            ushort4v pk;
#pragma unroll
            for (int r = 0; r < 4; ++r) pk[r] = f2bf(vac[rt][8 + ct][r] + bvv);
            *reinterpret_cast<ushort4v*>(&uA[(ct * 16 + lm) * A_LD + wrow]) = pk;
        }
    }
#pragma unroll
    for (int rt = 0; rt < 2; ++rt)
#pragma unroll
        for (int ct = 0; ct < 8; ++ct)
#pragma unroll
            for (int r = 0; r < 4; ++r)
                os[(rowbase + rt * 16 + lq * 4 + r) * C_ + ct * 16 + lm] = oac[rt][ct][r];
    __syncthreads();   // vT1 visible

    // ---------------- PV half1: out[:, 128:256) ----------------
    f32x4 oac2[2][8] = {};
#pragma unroll
    for (int kt = 0; kt < 4; ++kt) {
        short8 pa0 = *reinterpret_cast<const short8*>(&uC[(rowbase + lm) * P_LD + kt * 32 + lq * 8]);
        short8 pa1 = *reinterpret_cast<const short8*>(&uC[(rowbase + 16 + lm) * P_LD + kt * 32 + lq * 8]);
#pragma unroll
        for (int ct = 0; ct < 8; ++ct) {
            short8 vb = *reinterpret_cast<const short8*>(&uA[(ct * 16 + lm) * A_LD + kt * 32 + lq * 8]);
            oac2[0][ct] = MFMA16(pa0, vb, oac2[0][ct]);
            oac2[1][ct] = MFMA16(pa1, vb, oac2[1][ct]);
        }
    }
#pragma unroll
    for (int rt = 0; rt < 2; ++rt)
#pragma unroll
        for (int ct = 0; ct < 8; ++ct)
#pragma unroll
            for (int r = 0; r < 4; ++r)
                os[(rowbase + rt * 16 + lq * 4 + r) * C_ + 128 + ct * 16 + lm] = oac2[rt][ct][r];
}

extern "C" void kernel_launch(void* const* d_in, const int* in_sizes, int n_in,
                              void* d_out, int out_size, void* d_ws, size_t ws_size,
                              hipStream_t stream) {
    const float* x  = (const float*)d_in[0];
    const float* wq = (const float*)d_in[1];
    const float* bq = (const float*)d_in[2];
    const float* wk = (const float*)d_in[3];
    const float* bk = (const float*)d_in[4];
    const float* wv = (const float*)d_in[5];
    const float* bv = (const float*)d_in[6];
    float* out = (float*)d_out;
    u16* pack = (u16*)d_ws;   // wq_p: 8192, wk_p: 8192, wv_p: 65536 u16

    prep_pack<<<320, 256, 0, stream>>>(wq, wk, wv, pack);
    attn_fused<<<2048, 256, 0, stream>>>(x, pack, pack + 8192, pack + 16384,
                                         bq, bk, bv, out);
}

// Round 7
// 289.212 us; speedup vs baseline: 1.0039x; 1.0002x over previous
//
#include <hip/hip_runtime.h>

typedef __attribute__((ext_vector_type(8))) short short8;
typedef __attribute__((ext_vector_type(4))) float f32x4;
typedef __attribute__((ext_vector_type(4))) float float4v;
typedef __attribute__((ext_vector_type(4))) unsigned short ushort4v;
typedef unsigned short u16;

#define MFMA16(a, b, c) __builtin_amdgcn_mfma_f32_16x16x32_bf16((a), (b), (c), 0, 0, 0)

#define W_ 128
#define C_ 256
#define A_LD 136    // region A row stride: x-chunk [128][136] bf16, later vT-half [128][136]
#define QK_LD 40    // q,k [128][40] inside region C
#define P_LD 136    // p [128][136] over region C

__device__ __forceinline__ u16 f2bf(float f) {
    unsigned u = __builtin_bit_cast(unsigned, f);
    u += 0x7fffu + ((u >> 16) & 1u);   // RNE
    return (u16)(u >> 16);
}

// Pack weights into MFMA B-fragment order (bf16):
// pack[((kt*NCT + ct)*64 + lane)*8 + j] = w[kt*32 + (lane>>4)*8 + j][ct*16 + (lane&15)]
__global__ __launch_bounds__(256) void prep_pack(const float* __restrict__ wq,
                                                 const float* __restrict__ wk,
                                                 const float* __restrict__ wv,
                                                 u16* __restrict__ pack) {
    int t = blockIdx.x * 256 + threadIdx.x;   // 0 .. 81919
    int j = t & 7;
    int l = (t >> 3) & 63;
    int kr = ((l >> 4) << 3) + j;   // k offset within 32-chunk
    int lm = l & 15;
    if (t < 8192) {                 // wq: [256][32], NCT=2
        int g = t >> 9, ct = g & 1, kt = g >> 1;
        pack[t] = f2bf(wq[(kt * 32 + kr) * 32 + ct * 16 + lm]);
    } else if (t < 16384) {         // wk
        int u = t - 8192;
        int g = u >> 9, ct = g & 1, kt = g >> 1;
        pack[t] = f2bf(wk[(kt * 32 + kr) * 32 + ct * 16 + lm]);
    } else {                        // wv: [256][256], NCT=16
        int u = t - 16384;
        int g = u >> 9, ct = g & 15, kt = g >> 4;
        pack[t] = f2bf(wv[(kt * 32 + kr) * 256 + ct * 16 + lm]);
    }
}

// One block per (b,h) slice. 4 waves x 32 rows (R4 partition).
// LDS: regA 34816 + regC 34816 = 69632 B -> 2 blocks/CU, 8 waves/CU.
__global__ __launch_bounds__(256, 2) void attn_fused(
        const float* __restrict__ x,
        const u16* __restrict__ wq_p, const u16* __restrict__ wk_p,
        const u16* __restrict__ wv_p,
        const float* __restrict__ bq, const float* __restrict__ bk,
        const float* __restrict__ bv,
        float* __restrict__ out) {
    __shared__ u16 uA[W_ * A_LD];   // x chunk -> vT half0 -> vT half1
    __shared__ u16 uC[W_ * P_LD];   // q [0,5120) k [5120,10240) elems -> p [128][136]

    const int slice = blockIdx.x;        // b*H + h
    const int tid = threadIdx.x;
    const int lane = tid & 63;
    const int wid = tid >> 6;            // 0..3
    const int lm = lane & 15;
    const int lq = lane >> 4;
    const int rowbase = wid * 32;        // wave owns rows [rowbase, rowbase+32)
    const float* xs = x + (size_t)slice * (W_ * C_);

    f32x4 qa[2][2] = {};     // [rt][ct]
    f32x4 ka[2][2] = {};
    f32x4 vac[2][16] = {};   // v accum, all 256 cols

    // ---------------- Projections: stream x in two K=128 chunks ----------------
    for (int c = 0; c < 2; ++c) {
        {   // stage x[:, c*128 .. c*128+128) -> uA bf16
            int r0 = tid >> 5;               // 0..7
            int col = (tid & 31) * 4;        // 0..124
#pragma unroll
            for (int p = 0; p < 16; ++p) {
                int row = p * 8 + r0;
                float4v xv = *reinterpret_cast<const float4v*>(xs + row * C_ + c * 128 + col);
                ushort4v b4;
                b4[0] = f2bf(xv[0]); b4[1] = f2bf(xv[1]);
                b4[2] = f2bf(xv[2]); b4[3] = f2bf(xv[3]);
                *reinterpret_cast<ushort4v*>(&uA[row * A_LD + col]) = b4;
            }
        }
        __syncthreads();
#pragma unroll
        for (int kt = 0; kt < 4; ++kt) {
            short8 a0 = *reinterpret_cast<const short8*>(&uA[(rowbase + lm) * A_LD + kt * 32 + lq * 8]);
            short8 a1 = *reinterpret_cast<const short8*>(&uA[(rowbase + 16 + lm) * A_LD + kt * 32 + lq * 8]);
            int ktg = c * 4 + kt;
#pragma unroll
            for (int ct = 0; ct < 2; ++ct) {
                short8 bqf = *reinterpret_cast<const short8*>(wq_p + ((size_t)((ktg * 2 + ct) * 64 + lane)) * 8);
                short8 bkf = *reinterpret_cast<const short8*>(wk_p + ((size_t)((ktg * 2 + ct) * 64 + lane)) * 8);
                qa[0][ct] = MFMA16(a0, bqf, qa[0][ct]);
                qa[1][ct] = MFMA16(a1, bqf, qa[1][ct]);
                ka[0][ct] = MFMA16(a0, bkf, ka[0][ct]);
                ka[1][ct] = MFMA16(a1, bkf, ka[1][ct]);
            }
#pragma unroll
            for (int ct = 0; ct < 16; ++ct) {
                short8 bvf = *reinterpret_cast<const short8*>(wv_p + ((size_t)((ktg * 16 + ct) * 64 + lane)) * 8);
                vac[0][ct] = MFMA16(a0, bvf, vac[0][ct]);
                vac[1][ct] = MFMA16(a1, bvf, vac[1][ct]);
            }
        }
        __syncthreads();   // all chunk reads done before uA reuse
    }

    // ---------------- q,k (+bias) -> region C ; vT half0 (+bias) -> region A ----------------
#pragma unroll
    for (int rt = 0; rt < 2; ++rt)
#pragma unroll
        for (int ct = 0; ct < 2; ++ct) {
            float bqv = bq[ct * 16 + lm];
            float bkv = bk[ct * 16 + lm];
#pragma unroll
            for (int r = 0; r < 4; ++r) {
                int row = rowbase + rt * 16 + lq * 4 + r;
                uC[row * QK_LD + ct * 16 + lm] = f2bf(qa[rt][ct][r] + bqv);
                uC[W_ * QK_LD + row * QK_LD + ct * 16 + lm] = f2bf(ka[rt][ct][r] + bkv);
            }
        }
#pragma unroll
    for (int ct = 0; ct < 8; ++ct) {
        float bvv = bv[ct * 16 + lm];
#pragma unroll
        for (int rt = 0; rt < 2; ++rt) {
            int wrow = rowbase + rt * 16 + lq * 4;
            ushort4v pk;
#pragma unroll
            for (int r = 0; r < 4; ++r) pk[r] = f2bf(vac[rt][ct][r] + bvv);
            *reinterpret_cast<ushort4v*>(&uA[(ct * 16 + lm) * A_LD + wrow]) = pk;
        }
    }
    __syncthreads();   // q,k,vT0 visible to all waves

    // ---------------- scores = q @ k^T ----------------
    f32x4 s[2][8];
    {
        short8 aq0 = *reinterpret_cast<const short8*>(&uC[(rowbase + lm) * QK_LD + lq * 8]);
        short8 aq1 = *reinterpret_cast<const short8*>(&uC[(rowbase + 16 + lm) * QK_LD + lq * 8]);
        f32x4 zero = {0.f, 0.f, 0.f, 0.f};
#pragma unroll
        for (int ct = 0; ct < 8; ++ct) {
            short8 bk8 = *reinterpret_cast<const short8*>(&uC[W_ * QK_LD + (ct * 16 + lm) * QK_LD + lq * 8]);
            s[0][ct] = MFMA16(aq0, bk8, zero);
            s[1][ct] = MFMA16(aq1, bk8, zero);
        }
    }
    __syncthreads();   // all q/k reads done before p overwrites region C

    // ---------------- softmax -> p over region C (wave-local rows) ----------------
#pragma unroll
    for (int rt = 0; rt < 2; ++rt) {
#pragma unroll
        for (int r = 0; r < 4; ++r) {
            float m = s[rt][0][r];
#pragma unroll
            for (int ct = 1; ct < 8; ++ct) m = fmaxf(m, s[rt][ct][r]);
            m = fmaxf(m, __shfl_xor(m, 1));
            m = fmaxf(m, __shfl_xor(m, 2));
            m = fmaxf(m, __shfl_xor(m, 4));
            m = fmaxf(m, __shfl_xor(m, 8));
            float e[8];
            float sum = 0.f;
#pragma unroll
            for (int ct = 0; ct < 8; ++ct) {
                e[ct] = __expf(s[rt][ct][r] - m);
                sum += e[ct];
            }
            sum += __shfl_xor(sum, 1);
            sum += __shfl_xor(sum, 2);
            sum += __shfl_xor(sum, 4);
            sum += __shfl_xor(sum, 8);
            float inv = 1.0f / sum;
            int row = rowbase + rt * 16 + lq * 4 + r;
#pragma unroll
            for (int ct = 0; ct < 8; ++ct)
                uC[row * P_LD + ct * 16 + lm] = f2bf(e[ct] * inv);
        }
    }
    // p rows are wave-local (written+read by same wave) -> no barrier needed

    float* os = out + (size_t)slice * (W_ * C_);

    // ---------------- PV half0: out[:, 0:128) = p @ v0 ----------------
    f32x4 oac[2][8] = {};
#pragma unroll
    for (int kt = 0; kt < 4; ++kt) {
        short8 pa0 = *reinterpret_cast<const short8*>(&uC[(rowbase + lm) * P_LD + kt * 32 + lq * 8]);
        short8 pa1 = *reinterpret_cast<const short8*>(&uC[(rowbase + 16 + lm) * P_LD + kt * 32 + lq * 8]);
#pragma unroll
        for (int ct = 0; ct < 8; ++ct) {
            short8 vb = *reinterpret_cast<const short8*>(&uA[(ct * 16 + lm) * A_LD + kt * 32 + lq * 8]);
            oac[0][ct] = MFMA16(pa0, vb, oac[0][ct]);
            oac[1][ct] = MFMA16(pa1, vb, oac[1][ct]);
        }
    }
    __syncthreads();   // all vT0 reads done before vT1 overwrites region A

    // ---------------- vT half1 -> region A ; store out half0 ----------------
#pragma unroll
    for (int ct = 0; ct < 8; ++ct) {
        float bvv = bv[128 + ct * 16 + lm];
#pragma unroll
        for (int rt = 0; rt < 2; ++rt) {
            int wrow = rowbase + rt * 16 + lq * 4;
            ushort4v pk;
#pragma unroll
            for (int r = 0; r < 4; ++r) pk[r] = f2bf(vac[rt][8 + ct][r] + bvv);
            *reinterpret_cast<ushort4v*>(&uA[(ct * 16 + lm) * A_LD + wrow]) = pk;
        }
    }
#pragma unroll
    for (int rt = 0; rt < 2; ++rt)
#pragma unroll
        for (int ct = 0; ct < 8; ++ct)
#pragma unroll
            for (int r = 0; r < 4; ++r)
                os[(rowbase + rt * 16 + lq * 4 + r) * C_ + ct * 16 + lm] = oac[rt][ct][r];
    __syncthreads();   // vT1 visible

    // ---------------- PV half1: out[:, 128:256) ----------------
    f32x4 oac2[2][8] = {};
#pragma unroll
    for (int kt = 0; kt < 4; ++kt) {
        short8 pa0 = *reinterpret_cast<const short8*>(&uC[(rowbase + lm) * P_LD + kt * 32 + lq * 8]);
        short8 pa1 = *reinterpret_cast<const short8*>(&uC[(rowbase + 16 + lm) * P_LD + kt * 32 + lq * 8]);
#pragma unroll
        for (int ct = 0; ct < 8; ++ct) {
            short8 vb = *reinterpret_cast<const short8*>(&uA[(ct * 16 + lm) * A_LD + kt * 32 + lq * 8]);
            oac2[0][ct] = MFMA16(pa0, vb, oac2[0][ct]);
            oac2[1][ct] = MFMA16(pa1, vb, oac2[1][ct]);
        }
    }
#pragma unroll
    for (int rt = 0; rt < 2; ++rt)
#pragma unroll
        for (int ct = 0; ct < 8; ++ct)
#pragma unroll
            for (int r = 0; r < 4; ++r)
                os[(rowbase + rt * 16 + lq * 4 + r) * C_ + 128 + ct * 16 + lm] = oac2[rt][ct][r];
}

extern "C" void kernel_launch(void* const* d_in, const int* in_sizes, int n_in,
                              void* d_out, int out_size, void* d_ws, size_t ws_size,
                              hipStream_t stream) {
    const float* x  = (const float*)d_in[0];
    const float* wq = (const float*)d_in[1];
    const float* bq = (const float*)d_in[2];
    const float* wk = (const float*)d_in[3];
    const float* bk = (const float*)d_in[4];
    const float* wv = (const float*)d_in[5];
    const float* bv = (const float*)d_in[6];
    float* out = (float*)d_out;
    u16* pack = (u16*)d_ws;   // wq_p: 8192, wk_p: 8192, wv_p: 65536 u16

    prep_pack<<<320, 256, 0, stream>>>(wq, wk, wv, pack);
    attn_fused<<<2048, 256, 0, stream>>>(x, pack, pack + 8192, pack + 16384,
                                         bq, bk, bv, out);
}

// Round 8
// 195.455 us; speedup vs baseline: 1.4854x; 1.4797x over previous
//
#include <hip/hip_runtime.h>

typedef __attribute__((ext_vector_type(8))) short short8;
typedef __attribute__((ext_vector_type(16))) float f32x16;
typedef __attribute__((ext_vector_type(4))) float float4v;
typedef __attribute__((ext_vector_type(4))) unsigned short ushort4v;
typedef unsigned short u16;

#define MFMA32(a, b, c) __builtin_amdgcn_mfma_f32_32x32x16_bf16((a), (b), (c), 0, 0, 0)

#define W_ 128
#define C_ 256
#define X_LD 136     // x chunk [128][136] bf16 in region A
#define QK_LD 40     // q,k [128][40] in region A
#define P_LD 136     // p [128][136] over region A
#define VT_LD 136    // vT half [128][136] over region B
#define SLAB_U16 5120  // one K=16 weight slab: 10 KB = 10 frags x 512 u16

__device__ __forceinline__ u16 f2bf(float f) {
    unsigned u = __builtin_bit_cast(unsigned, f);
    u += 0x7fffu + ((u >> 16) & 1u);   // RNE
    return (u16)(u >> 16);
}

__device__ __forceinline__ f32x16 zero16() {
    f32x16 z;
#pragma unroll
    for (int i = 0; i < 16; ++i) z[i] = 0.f;
    return z;
}

// global -> LDS direct copy, 16B per lane. LDS dest is wave-uniform base;
// HW writes lane l at dst + l*16 (m97/m104 semantics).
__device__ __forceinline__ void gll16(const u16* g, const u16* l) {
    auto s = (const __attribute__((address_space(1))) unsigned*)((uintptr_t)g);
    auto d = (__attribute__((address_space(3))) unsigned*)((unsigned)(uintptr_t)l);
    __builtin_amdgcn_global_load_lds(s, d, 16, 0, 0);
}

// raw barrier with LDS drain + scheduler fence (rule 18)
__device__ __forceinline__ void wg_barrier() {
    asm volatile("s_waitcnt lgkmcnt(0)" ::: "memory");
    __builtin_amdgcn_sched_barrier(0);
    __builtin_amdgcn_s_barrier();
}

// Pack weights into per-ktg slabs of 10 B-fragments (32x32x16 layout):
// pack[ktg*5120 + f*512 + l*8 + j] = w[ktg*16 + (l>>5)*8 + j][col(f, l&31)]
// f=0: wq (col = l&31), f=1: wk, f=2+ci: wv col = ci*32 + (l&31)
__global__ __launch_bounds__(256) void prep_pack(const float* __restrict__ wq,
                                                 const float* __restrict__ wk,
                                                 const float* __restrict__ wv,
                                                 u16* __restrict__ pack) {
    int t = blockIdx.x * 256 + threadIdx.x;   // 0 .. 81919
    int j = t & 7;
    int l = (t >> 3) & 63;
    int g = t >> 9;            // 0..159
    int f = g % 10;
    int ktg = g / 10;          // 0..15
    int k = ktg * 16 + ((l >> 5) << 3) + j;
    int c = l & 31;
    float w;
    if (f == 0)      w = wq[k * 32 + c];
    else if (f == 1) w = wk[k * 32 + c];
    else             w = wv[k * 256 + (f - 2) * 32 + c];
    pack[t] = f2bf(w);
}

// One block per (b,h) slice. 4 waves x 32 rows. 32x32x16 MFMA.
// LDS: regA 34816 + regB 34816 = 69632 B -> 2 blocks/CU.
__global__ __launch_bounds__(256, 2) void attn_fused(
        const float* __restrict__ x,
        const u16* __restrict__ pack,
        const float* __restrict__ bq, const float* __restrict__ bk,
        const float* __restrict__ bv,
        float* __restrict__ out) {
    __shared__ u16 uA[17408];   // x chunk -> q[0,5120)+k[5120,10240) -> p[128][136]
    __shared__ u16 uB[17408];   // weight slabs (3 x 5120) -> vT halves [128][136]

    const int slice = blockIdx.x;
    const int tid = threadIdx.x;
    const int lane = tid & 63;
    const int wid = tid >> 6;          // 0..3
    const int lm = lane & 31;
    const int l5 = lane >> 5;          // 0/1
    const int rowbase = wid * 32;      // wave owns rows [rowbase, rowbase+32)
    const float* xs = x + (size_t)slice * (W_ * C_);

    // slab issue assignment: wave w handles issues {w, w+4}; waves 0,1 add {8,9}.
    // own issues per slab n_w = 3 (wid<2) else 2.

    f32x16 qa = zero16();
    f32x16 ka = zero16();
    f32x16 vac[8];
#pragma unroll
    for (int ci = 0; ci < 8; ++ci) vac[ci] = zero16();

    // ---- prologue: issue slabs 0,1 into bufs 0,1 ----
#pragma unroll
    for (int sb = 0; sb < 2; ++sb) {
        const u16* gs = pack + sb * SLAB_U16 + lane * 8;
        const u16* ls = &uB[sb * SLAB_U16];
        gll16(gs + wid * 512, ls + wid * 512);
        gll16(gs + (wid + 4) * 512, ls + (wid + 4) * 512);
        if (wid < 2) gll16(gs + (8 + wid) * 512, ls + (8 + wid) * 512);
    }

    // ---------------- Projections: stream x in two K=128 chunks ----------------
    for (int c = 0; c < 2; ++c) {
        if (c == 1) wg_barrier();   // all chunk-0 uA reads done before restage
        {   // stage x[:, c*128 .. +128) -> uA bf16
            int r0 = tid >> 5;               // 0..7
            int col = (tid & 31) * 4;        // 0..124
#pragma unroll
            for (int p = 0; p < 16; ++p) {
                int row = p * 8 + r0;
                float4v xv = *reinterpret_cast<const float4v*>(xs + row * C_ + c * 128 + col);
                ushort4v b4;
                b4[0] = f2bf(xv[0]); b4[1] = f2bf(xv[1]);
                b4[2] = f2bf(xv[2]); b4[3] = f2bf(xv[3]);
                *reinterpret_cast<ushort4v*>(&uA[row * X_LD + col]) = b4;
            }
        }
        __syncthreads();   // drains vmcnt+lgkm: x visible, slabs for this chunk landed

        for (int kt = 0; kt < 8; ++kt) {
            const int ktg = c * 8 + kt;
            if (kt != 0) {
                // prove own slab-ktg issues complete, then sync all waves
                if (ktg == 15)      { asm volatile("s_waitcnt vmcnt(0)" ::: "memory"); }
                else if (wid < 2)   { asm volatile("s_waitcnt vmcnt(3)" ::: "memory"); }
                else                { asm volatile("s_waitcnt vmcnt(2)" ::: "memory"); }
                wg_barrier();
            }
            // prefetch slab ktg+2 into buf (ktg+2)%3 (its last readers finished iter ktg-1)
            if (ktg < 14) {
                const int pb = (ktg + 2) % 3;
                const u16* gs = pack + (size_t)(ktg + 2) * SLAB_U16 + lane * 8;
                const u16* ls = &uB[pb * SLAB_U16];
                gll16(gs + wid * 512, ls + wid * 512);
                gll16(gs + (wid + 4) * 512, ls + (wid + 4) * 512);
                if (wid < 2) gll16(gs + (8 + wid) * 512, ls + (8 + wid) * 512);
            }
            // consume slab ktg
            const u16* sl = &uB[(ktg % 3) * SLAB_U16];
            short8 af = *reinterpret_cast<const short8*>(&uA[(rowbase + lm) * X_LD + kt * 16 + l5 * 8]);
            short8 bqf = *reinterpret_cast<const short8*>(&sl[lane * 8]);
            short8 bkf = *reinterpret_cast<const short8*>(&sl[512 + lane * 8]);
            qa = MFMA32(af, bqf, qa);
            ka = MFMA32(af, bkf, ka);
#pragma unroll
            for (int ci = 0; ci < 8; ++ci) {
                short8 bvf = *reinterpret_cast<const short8*>(&sl[(2 + ci) * 512 + lane * 8]);
                vac[ci] = MFMA32(af, bvf, vac[ci]);
            }
        }
    }

    wg_barrier();   // all proj uA/uB reads done (vmcnt already proven at ktg=15)

    // ---------------- q,k (+bias) -> region A ; vT half0 (+bias) -> region B ----------------
    {
        float bqv = bq[lm];
        float bkv = bk[lm];
#pragma unroll
        for (int e = 0; e < 16; ++e) {
            int row = rowbase + (e & 3) + 8 * (e >> 2) + 4 * l5;
            uA[row * QK_LD + lm] = f2bf(qa[e] + bqv);
            uA[5120 + row * QK_LD + lm] = f2bf(ka[e] + bkv);
        }
    }
#pragma unroll
    for (int ci = 0; ci < 4; ++ci) {
        float bvv = bv[ci * 32 + lm];
#pragma unroll
        for (int eb = 0; eb < 4; ++eb) {   // pack 4 consecutive w' per write
            int w0 = rowbase + 8 * eb + 4 * l5;
            ushort4v pk;
#pragma unroll
            for (int r = 0; r < 4; ++r) pk[r] = f2bf(vac[ci][eb * 4 + r] + bvv);
            *reinterpret_cast<ushort4v*>(&uB[(ci * 32 + lm) * VT_LD + w0]) = pk;
        }
    }
    wg_barrier();   // q,k,vT0 visible

    // ---------------- scores = q @ k^T ----------------
    f32x16 s[4];
#pragma unroll
    for (int c2 = 0; c2 < 4; ++c2) s[c2] = zero16();
#pragma unroll
    for (int kt = 0; kt < 2; ++kt) {
        short8 aq = *reinterpret_cast<const short8*>(&uA[(rowbase + lm) * QK_LD + kt * 16 + l5 * 8]);
#pragma unroll
        for (int c2 = 0; c2 < 4; ++c2) {
            short8 bkf = *reinterpret_cast<const short8*>(&uA[5120 + (c2 * 32 + lm) * QK_LD + kt * 16 + l5 * 8]);
            s[c2] = MFMA32(aq, bkf, s[c2]);
        }
    }
    wg_barrier();   // all q/k reads done before p overwrites region A

    // ---------------- softmax -> p over region A ----------------
#pragma unroll
    for (int e = 0; e < 16; ++e) {
        float m = fmaxf(fmaxf(s[0][e], s[1][e]), fmaxf(s[2][e], s[3][e]));
        m = fmaxf(m, __shfl_xor(m, 1));
        m = fmaxf(m, __shfl_xor(m, 2));
        m = fmaxf(m, __shfl_xor(m, 4));
        m = fmaxf(m, __shfl_xor(m, 8));
        m = fmaxf(m, __shfl_xor(m, 16));
        float e0 = __expf(s[0][e] - m);
        float e1 = __expf(s[1][e] - m);
        float e2 = __expf(s[2][e] - m);
        float e3 = __expf(s[3][e] - m);
        float sum = (e0 + e1) + (e2 + e3);
        sum += __shfl_xor(sum, 1);
        sum += __shfl_xor(sum, 2);
        sum += __shfl_xor(sum, 4);
        sum += __shfl_xor(sum, 8);
        sum += __shfl_xor(sum, 16);
        float inv = 1.0f / sum;
        int row = rowbase + (e & 3) + 8 * (e >> 2) + 4 * l5;
        uA[row * P_LD + lm] = f2bf(e0 * inv);
        uA[row * P_LD + 32 + lm] = f2bf(e1 * inv);
        uA[row * P_LD + 64 + lm] = f2bf(e2 * inv);
        uA[row * P_LD + 96 + lm] = f2bf(e3 * inv);
    }
    // p rows are wave-local (PV A-frags read own rows only) -> no barrier

    float* os = out + (size_t)slice * (W_ * C_);

    // ---------------- PV half0: out[:, 0:128) ----------------
    f32x16 oc[4];
#pragma unroll
    for (int c2 = 0; c2 < 4; ++c2) oc[c2] = zero16();
#pragma unroll
    for (int kt = 0; kt < 8; ++kt) {
        short8 pa = *reinterpret_cast<const short8*>(&uA[(rowbase + lm) * P_LD + kt * 16 + l5 * 8]);
#pragma unroll
        for (int c2 = 0; c2 < 4; ++c2) {
            short8 vb = *reinterpret_cast<const short8*>(&uB[(c2 * 32 + lm) * VT_LD + kt * 16 + l5 * 8]);
            oc[c2] = MFMA32(pa, vb, oc[c2]);
        }
    }
    wg_barrier();   // vT0 reads done before vT1 overwrite

    // ---------------- vT half1 -> region B ; store out half0 ----------------
#pragma unroll
    for (int ci = 0; ci < 4; ++ci) {
        float bvv = bv[128 + ci * 32 + lm];
#pragma unroll
        for (int eb = 0; eb < 4; ++eb) {
            int w0 = rowbase + 8 * eb + 4 * l5;
            ushort4v pk;
#pragma unroll
            for (int r = 0; r < 4; ++r) pk[r] = f2bf(vac[4 + ci][eb * 4 + r] + bvv);
            *reinterpret_cast<ushort4v*>(&uB[(ci * 32 + lm) * VT_LD + w0]) = pk;
        }
    }
#pragma unroll
    for (int c2 = 0; c2 < 4; ++c2)
#pragma unroll
        for (int e = 0; e < 16; ++e) {
            int row = rowbase + (e & 3) + 8 * (e >> 2) + 4 * l5;
            os[row * C_ + c2 * 32 + lm] = oc[c2][e];
        }
    wg_barrier();   // vT1 visible

    // ---------------- PV half1: out[:, 128:256) ----------------
#pragma unroll
    for (int c2 = 0; c2 < 4; ++c2) oc[c2] = zero16();
#pragma unroll
    for (int kt = 0; kt < 8; ++kt) {
        short8 pa = *reinterpret_cast<const short8*>(&uA[(rowbase + lm) * P_LD + kt * 16 + l5 * 8]);
#pragma unroll
        for (int c2 = 0; c2 < 4; ++c2) {
            short8 vb = *reinterpret_cast<const short8*>(&uB[(c2 * 32 + lm) * VT_LD + kt * 16 + l5 * 8]);
            oc[c2] = MFMA32(pa, vb, oc[c2]);
        }
    }
#pragma unroll
    for (int c2 = 0; c2 < 4; ++c2)
#pragma unroll
        for (int e = 0; e < 16; ++e) {
            int row = rowbase + (e & 3) + 8 * (e >> 2) + 4 * l5;
            os[row * C_ + 128 + c2 * 32 + lm] = oc[c2][e];
        }
}

extern "C" void kernel_launch(void* const* d_in, const int* in_sizes, int n_in,
                              void* d_out, int out_size, void* d_ws, size_t ws_size,
                              hipStream_t stream) {
    const float* x  = (const float*)d_in[0];
    const float* wq = (const float*)d_in[1];
    const float* bq = (const float*)d_in[2];
    const float* wk = (const float*)d_in[3];
    const float* bk = (const float*)d_in[4];
    const float* wv = (const float*)d_in[5];
    const float* bv = (const float*)d_in[6];
    float* out = (float*)d_out;
    u16* pack = (u16*)d_ws;   // 16 slabs x 5120 u16 = 160 KB

    prep_pack<<<320, 256, 0, stream>>>(wq, wk, wv, pack);
    attn_fused<<<2048, 256, 0, stream>>>(x, pack, bq, bk, bv, out);
}

// Round 9
// 165.394 us; speedup vs baseline: 1.7554x; 1.1818x over previous
//
#include <hip/hip_runtime.h>

typedef __attribute__((ext_vector_type(8))) short short8;
typedef __attribute__((ext_vector_type(16))) float f32x16;
typedef __attribute__((ext_vector_type(4))) float float4v;
typedef __attribute__((ext_vector_type(4))) unsigned short ushort4v;
typedef unsigned short u16;

#define MFMA32(a, b, c) __builtin_amdgcn_mfma_f32_32x32x16_bf16((a), (b), (c), 0, 0, 0)

#define W_ 128
#define C_ 256
#define X_LD 136     // x chunk [128][136] bf16 in region A
#define VT_LD 136    // vT half [128][136] over region A
#define QK_LD 40     // q,k [128][40] in region C
#define P_LD 136     // p [128][136] over region C

__device__ __forceinline__ u16 f2bf(float f) {
    unsigned u = __builtin_bit_cast(unsigned, f);
    u += 0x7fffu + ((u >> 16) & 1u);   // RNE
    return (u16)(u >> 16);
}

__device__ __forceinline__ f32x16 zero16() {
    f32x16 z;
#pragma unroll
    for (int i = 0; i < 16; ++i) z[i] = 0.f;
    return z;
}

// global -> LDS direct copy, 16B per lane (dst wave-uniform, src per-lane).
__device__ __forceinline__ void gll16(const u16* g, const u16* l) {
    auto s = (const __attribute__((address_space(1))) unsigned*)((uintptr_t)g);
    auto d = (__attribute__((address_space(3))) unsigned*)((unsigned)(uintptr_t)l);
    __builtin_amdgcn_global_load_lds(s, d, 16, 0, 0);
}

// raw barrier: drain LDS ops only (global stores keep flowing), fence scheduler
__device__ __forceinline__ void wg_barrier() {
    asm volatile("s_waitcnt lgkmcnt(0)" ::: "memory");
    __builtin_amdgcn_sched_barrier(0);
    __builtin_amdgcn_s_barrier();
}

// Pack weights into MFMA fragment order (bf16), 16 slabs x 10 frags x 512 u16:
// pack[ktg*5120 + f*512 + l*8 + j] = w[ktg*16 + (l>>5)*8 + j][col(f, l&31)]
// f=0: wq, f=1: wk, f=2+ci: wv col = ci*32 + (l&31). Same layout serves B-frags
// (q,k: col=lane&31) and A-frags (vT: row=lane&31) by A/B symmetry.
__global__ __launch_bounds__(256) void prep_pack(const float* __restrict__ wq,
                                                 const float* __restrict__ wk,
                                                 const float* __restrict__ wv,
                                                 u16* __restrict__ pack) {
    int t = blockIdx.x * 256 + threadIdx.x;   // 0 .. 81919
    int j = t & 7;
    int l = (t >> 3) & 63;
    int g = t >> 9;            // 0..159
    int f = g % 10;
    int ktg = g / 10;          // 0..15
    int k = ktg * 16 + ((l >> 5) << 3) + j;
    int c = l & 31;
    float w;
    if (f == 0)      w = wq[k * 32 + c];
    else if (f == 1) w = wk[k * 32 + c];
    else             w = wv[k * 256 + (f - 2) * 32 + c];
    pack[t] = f2bf(w);
}

// One block per (b,h) slice. 4 waves x 32 rows. 32x32x16 MFMA.
// LDS: regA 34816 + regC 34816 = 69632 B -> 2 blocks/CU.
// qk weights: LDS (loaded once). v weights: streamed to registers (L2-hot).
// Projection loop is barrier-free per wave.
__global__ __launch_bounds__(256, 2) void attn_fused(
        const float* __restrict__ x,
        const u16* __restrict__ pack,
        const float* __restrict__ bq, const float* __restrict__ bk,
        const float* __restrict__ bv,
        float* __restrict__ out) {
    __shared__ u16 uA[17408];   // x chunk -> vT half0 -> vT half1
    __shared__ u16 uC[17408];   // qk weights (16384) -> q[0,5120)+k[5120,10240) -> p

    const int slice = blockIdx.x;
    const int tid = threadIdx.x;
    const int lane = tid & 63;
    const int wid = tid >> 6;          // 0..3
    const int lm = lane & 31;
    const int l5 = lane >> 5;          // 0/1
    const int rowbase = wid * 32;      // wave owns w-rows [rowbase, rowbase+32)
    const float* xs = x + (size_t)slice * (W_ * C_);

    // v weight streams: wave wid owns v-col tiles {wid, wid+4}
    const u16* vw0 = pack + (size_t)(2 + wid) * 512 + lane * 8;
    const u16* vw1 = pack + (size_t)(2 + wid + 4) * 512 + lane * 8;

    f32x16 qa = zero16();
    f32x16 ka = zero16();
    f32x16 vac0[4], vac1[4];   // [nn]: vT tile x w-subtile, N=128
#pragma unroll
    for (int nn = 0; nn < 4; ++nn) { vac0[nn] = zero16(); vac1[nn] = zero16(); }

    // ---- prologue: qk weights -> uC via global_load_lds (16 frags x 1KB) ----
#pragma unroll
    for (int i = 0; i < 4; ++i) {
        int ks = wid * 4 + i;
        const u16* gs = pack + (size_t)ks * 5120 + lane * 8;
        gll16(gs, &uC[(ks * 2 + 0) * 512]);
        gll16(gs + 512, &uC[(ks * 2 + 1) * 512]);
    }

    // ---------------- Projections: stream x in two K=128 chunks ----------------
    for (int c = 0; c < 2; ++c) {
        if (c == 1) wg_barrier();   // all chunk-0 uA reads done before restage
        {   // stage x[:, c*128 .. +128) -> uA bf16
            int r0 = tid >> 5;               // 0..7
            int col = (tid & 31) * 4;        // 0..124
#pragma unroll
            for (int p = 0; p < 16; ++p) {
                int row = p * 8 + r0;
                float4v xv = *reinterpret_cast<const float4v*>(xs + row * C_ + c * 128 + col);
                ushort4v b4;
                b4[0] = f2bf(xv[0]); b4[1] = f2bf(xv[1]);
                b4[2] = f2bf(xv[2]); b4[3] = f2bf(xv[3]);
                *reinterpret_cast<ushort4v*>(&uA[row * X_LD + col]) = b4;
            }
        }
        __syncthreads();   // x visible; (c==0) qk-weight gll landed (vmcnt drained)

        // v-weight software pipeline, depth 2
        short8 wf0[4], wf1[4];
        wf0[0] = *reinterpret_cast<const short8*>(vw0 + (size_t)(c * 8 + 0) * 5120);
        wf1[0] = *reinterpret_cast<const short8*>(vw1 + (size_t)(c * 8 + 0) * 5120);
        wf0[1] = *reinterpret_cast<const short8*>(vw0 + (size_t)(c * 8 + 1) * 5120);
        wf1[1] = *reinterpret_cast<const short8*>(vw1 + (size_t)(c * 8 + 1) * 5120);

#pragma unroll
        for (int kt = 0; kt < 8; ++kt) {
            const int ks = c * 8 + kt;
            if (kt < 6) {
                wf0[(kt + 2) & 3] = *reinterpret_cast<const short8*>(vw0 + (size_t)(ks + 2) * 5120);
                wf1[(kt + 2) & 3] = *reinterpret_cast<const short8*>(vw1 + (size_t)(ks + 2) * 5120);
            }
            // x fragments: rows nn*32+lm, k-slice kt*16 + l5*8 (A- and B-layouts coincide)
            short8 xf[4];
#pragma unroll
            for (int nn = 0; nn < 4; ++nn)
                xf[nn] = *reinterpret_cast<const short8*>(&uA[(nn * 32 + lm) * X_LD + kt * 16 + l5 * 8]);
            short8 aqk = *reinterpret_cast<const short8*>(&uA[(rowbase + lm) * X_LD + kt * 16 + l5 * 8]);
            short8 bq8 = *reinterpret_cast<const short8*>(&uC[(ks * 2 + 0) * 512 + lane * 8]);
            short8 bk8 = *reinterpret_cast<const short8*>(&uC[(ks * 2 + 1) * 512 + lane * 8]);
            qa = MFMA32(aqk, bq8, qa);
            ka = MFMA32(aqk, bk8, ka);
#pragma unroll
            for (int nn = 0; nn < 4; ++nn) {
                vac0[nn] = MFMA32(wf0[kt & 3], xf[nn], vac0[nn]);   // D[vcol][w'] = vT
                vac1[nn] = MFMA32(wf1[kt & 3], xf[nn], vac1[nn]);
            }
        }
    }
    wg_barrier();   // all x/qk-weight reads done before uA/uC are repurposed

    // ---------------- q,k (+bias) -> region C ; vT half0 (tile wid) -> region A ----------------
    {
        float bqv = bq[lm];
        float bkv = bk[lm];
#pragma unroll
        for (int e = 0; e < 16; ++e) {
            int row = rowbase + (e & 3) + 8 * (e >> 2) + 4 * l5;
            uC[row * QK_LD + lm] = f2bf(qa[e] + bqv);
            uC[5120 + row * QK_LD + lm] = f2bf(ka[e] + bkv);
        }
    }
#pragma unroll
    for (int e = 0; e < 16; ++e) {
        int cl = (e & 3) + 8 * (e >> 2) + 4 * l5;     // v-col within tile
        float bvv = bv[wid * 32 + cl];
#pragma unroll
        for (int nn = 0; nn < 4; ++nn)
            uA[(wid * 32 + cl) * VT_LD + nn * 32 + lm] = f2bf(vac0[nn][e] + bvv);
    }
    wg_barrier();   // q,k,vT0 visible

    // ---------------- scores = q @ k^T ----------------
    f32x16 s[4];
#pragma unroll
    for (int c2 = 0; c2 < 4; ++c2) s[c2] = zero16();
#pragma unroll
    for (int kt = 0; kt < 2; ++kt) {
        short8 aq = *reinterpret_cast<const short8*>(&uC[(rowbase + lm) * QK_LD + kt * 16 + l5 * 8]);
#pragma unroll
        for (int c2 = 0; c2 < 4; ++c2) {
            short8 bkf = *reinterpret_cast<const short8*>(&uC[5120 + (c2 * 32 + lm) * QK_LD + kt * 16 + l5 * 8]);
            s[c2] = MFMA32(aq, bkf, s[c2]);
        }
    }
    wg_barrier();   // all q/k reads done before p overwrites region C

    // ---------------- softmax -> p over region C ----------------
#pragma unroll
    for (int e = 0; e < 16; ++e) {
        float m = fmaxf(fmaxf(s[0][e], s[1][e]), fmaxf(s[2][e], s[3][e]));
        m = fmaxf(m, __shfl_xor(m, 1));
        m = fmaxf(m, __shfl_xor(m, 2));
        m = fmaxf(m, __shfl_xor(m, 4));
        m = fmaxf(m, __shfl_xor(m, 8));
        m = fmaxf(m, __shfl_xor(m, 16));
        float e0 = __expf(s[0][e] - m);
        float e1 = __expf(s[1][e] - m);
        float e2 = __expf(s[2][e] - m);
        float e3 = __expf(s[3][e] - m);
        float sum = (e0 + e1) + (e2 + e3);
        sum += __shfl_xor(sum, 1);
        sum += __shfl_xor(sum, 2);
        sum += __shfl_xor(sum, 4);
        sum += __shfl_xor(sum, 8);
        sum += __shfl_xor(sum, 16);
        float inv = 1.0f / sum;
        int row = rowbase + (e & 3) + 8 * (e >> 2) + 4 * l5;
        uC[row * P_LD + lm] = f2bf(e0 * inv);
        uC[row * P_LD + 32 + lm] = f2bf(e1 * inv);
        uC[row * P_LD + 64 + lm] = f2bf(e2 * inv);
        uC[row * P_LD + 96 + lm] = f2bf(e3 * inv);
    }
    // p rows are wave-local (PV A-frags read own rows only) -> no barrier

    float* os = out + (size_t)slice * (W_ * C_);

    // ---------------- PV half0: out[:, 0:128) ----------------
    f32x16 oc[4];
#pragma unroll
    for (int c2 = 0; c2 < 4; ++c2) oc[c2] = zero16();
#pragma unroll
    for (int kt = 0; kt < 8; ++kt) {
        short8 pa = *reinterpret_cast<const short8*>(&uC[(rowbase + lm) * P_LD + kt * 16 + l5 * 8]);
#pragma unroll
        for (int c2 = 0; c2 < 4; ++c2) {
            short8 vb = *reinterpret_cast<const short8*>(&uA[(c2 * 32 + lm) * VT_LD + kt * 16 + l5 * 8]);
            oc[c2] = MFMA32(pa, vb, oc[c2]);
        }
    }
    wg_barrier();   // vT0 reads done before vT1 overwrite

    // ---------------- vT half1 (tile wid+4) -> region A ; store out half0 ----------------
#pragma unroll
    for (int e = 0; e < 16; ++e) {
        int cl = (e & 3) + 8 * (e >> 2) + 4 * l5;
        float bvv = bv[128 + wid * 32 + cl];
#pragma unroll
        for (int nn = 0; nn < 4; ++nn)
            uA[(wid * 32 + cl) * VT_LD + nn * 32 + lm] = f2bf(vac1[nn][e] + bvv);
    }
#pragma unroll
    for (int c2 = 0; c2 < 4; ++c2)
#pragma unroll
        for (int e = 0; e < 16; ++e) {
            int row = rowbase + (e & 3) + 8 * (e >> 2) + 4 * l5;
            os[row * C_ + c2 * 32 + lm] = oc[c2][e];
        }
    wg_barrier();   // vT1 visible (stores keep draining in background)

    // ---------------- PV half1: out[:, 128:256) ----------------
#pragma unroll
    for (int c2 = 0; c2 < 4; ++c2) oc[c2] = zero16();
#pragma unroll
    for (int kt = 0; kt < 8; ++kt) {
        short8 pa = *reinterpret_cast<const short8*>(&uC[(rowbase + lm) * P_LD + kt * 16 + l5 * 8]);
#pragma unroll
        for (int c2 = 0; c2 < 4; ++c2) {
            short8 vb = *reinterpret_cast<const short8*>(&uA[(c2 * 32 + lm) * VT_LD + kt * 16 + l5 * 8]);
            oc[c2] = MFMA32(pa, vb, oc[c2]);
        }
    }
#pragma unroll
    for (int c2 = 0; c2 < 4; ++c2)
#pragma unroll
        for (int e = 0; e < 16; ++e) {
            int row = rowbase + (e & 3) + 8 * (e >> 2) + 4 * l5;
            os[row * C_ + 128 + c2 * 32 + lm] = oc[c2][e];
        }
}

extern "C" void kernel_launch(void* const* d_in, const int* in_sizes, int n_in,
                              void* d_out, int out_size, void* d_ws, size_t ws_size,
                              hipStream_t stream) {
    const float* x  = (const float*)d_in[0];
    const float* wq = (const float*)d_in[1];
    const float* bq = (const float*)d_in[2];
    const float* wk = (const float*)d_in[3];
    const float* bk = (const float*)d_in[4];
    const float* wv = (const float*)d_in[5];
    const float* bv = (const float*)d_in[6];
    float* out = (float*)d_out;
    u16* pack = (u16*)d_ws;   // 16 slabs x 5120 u16 = 160 KB

    prep_pack<<<320, 256, 0, stream>>>(wq, wk, wv, pack);
    attn_fused<<<2048, 256, 0, stream>>>(x, pack, bq, bk, bv, out);
}